// Round 6
// baseline (191.420 us; speedup 1.0000x reference)
//
#include <hip/hip_runtime.h>

// OptPosEncBatch: per-point multi-feature 1D-linear codebook interpolation.
// coords [B=8, P=65536, F=3] f32, idx [B] i32, shape_code [C=64, S*F*CN=3072] f32
// out [B, P, C=64] f32.
//
// R4 post-mortem: two latency-targeted fixes on the LDS design = 0. Diagnosis:
// lgkmcnt is IN-ORDER -- coord ds_read (newest lgkm op) forces lgkmcnt(0),
// draining the prefetched gather queue every iteration; pipeline never forms.
// R5: remove LDS entirely. Pre-transpose codebook to d_ws (code_t[j][c], 768KB,
// L1/L2-resident); main kernel gathers 256B rows via global_load_dwordx4
// (homogeneous vmcnt queue, counted waits don't block on stores), 24 waves/CU.

#define CODE_NUM 64
#define NFEAT 3
#define NCHAN 64
#define NB 8
#define NP 65536
#define SLICE (CODE_NUM * NFEAT)          // 192 rows per batch slice
#define ROW_STRIDE 3072                   // SHAPE_NUM * NFEAT * CODE_NUM
#define CODE_T_ELEMS (ROW_STRIDE * NCHAN) // 196608 floats = 768 KB

// code_t[j][c] = shape_code[c][j]; writes coalesced, reads L1-amortized
// (16 consecutive j share a 64B line per fixed c). Fully overwrites the
// d_ws region every call (poison-safe).
__global__ __launch_bounds__(256)
void transpose_kernel(const float* __restrict__ shape_code,
                      float* __restrict__ code_t) {
    const int t = blockIdx.x * 256 + threadIdx.x;   // t = j*64 + c
    const int c = t & 63;
    const int j = t >> 6;
    code_t[t] = shape_code[(size_t)c * ROW_STRIDE + j];
}

#define NTHREADS 256
#define BLOCKS_PER_BATCH 256
#define PTS_PER_BLOCK (NP / BLOCKS_PER_BATCH)   // 256
#define PTS_PER_ITER (NTHREADS / 16)            // 16 points per iteration
#define NIT (PTS_PER_BLOCK / PTS_PER_ITER)      // 16

__global__ __launch_bounds__(NTHREADS, 6)   // 6 waves/EU = 24 waves/CU, ~84 VGPR cap
void posenc_kernel(const float* __restrict__ coords,
                   const int* __restrict__ idx,
                   const float* __restrict__ code_t,
                   float* __restrict__ out) {
    const int bx    = blockIdx.x;
    const int b     = bx >> 8;                          // batch
    const int chunk = (bx & (BLOCKS_PER_BATCH - 1)) * PTS_PER_BLOCK;
    const int tid   = threadIdx.x;
    const int gl    = tid & 15;                         // channel group
    const int pofs  = tid >> 4;                         // 0..15

    const size_t bp0 = (size_t)b * NP;
    // per-batch slice base + this lane's channel offset
    const float* cb0 = code_t + (size_t)idx[b] * (SLICE * NCHAN) + gl * 4;
    const float* cb1 = cb0 + CODE_NUM * NCHAN;
    const float* cb2 = cb1 + CODE_NUM * NCHAN;
    const float* cp  = coords + (bp0 + chunk) * NFEAT;
    float*       og  = out + (bp0 + chunk) * NCHAN + gl * 4;

    for (int it = 0; it < NIT; ++it) {
        const int lp = it * PTS_PER_ITER + pofs;

        // 16-lane broadcast reads; a wave's 4 points span 48 contiguous bytes
        const float x0 = cp[lp * 3 + 0];
        const float x1 = cp[lp * 3 + 1];
        const float x2 = cp[lp * 3 + 2];

        const float g0 = fmaf(x0, 31.5f, 31.5f);
        const float g1 = fmaf(x1, 31.5f, 31.5f);
        const float g2 = fmaf(x2, 31.5f, 31.5f);
        int i0 = (int)floorf(g0); i0 = max(0, min(i0, CODE_NUM - 2));
        int i1 = (int)floorf(g1); i1 = max(0, min(i1, CODE_NUM - 2));
        int i2 = (int)floorf(g2); i2 = max(0, min(i2, CODE_NUM - 2));
        const float w1a = g0 - (float)i0, w0a = 1.0f - w1a;
        const float w1b = g1 - (float)i1, w0b = 1.0f - w1b;
        const float w1c = g2 - (float)i2, w0c = 1.0f - w1c;

        // six independent 256B-row gathers (4 groups/wave -> 4x256B segments each)
        const float4 a0 = *reinterpret_cast<const float4*>(cb0 + i0 * NCHAN);
        const float4 a1 = *reinterpret_cast<const float4*>(cb0 + i0 * NCHAN + NCHAN);
        const float4 b0 = *reinterpret_cast<const float4*>(cb1 + i1 * NCHAN);
        const float4 b1 = *reinterpret_cast<const float4*>(cb1 + i1 * NCHAN + NCHAN);
        const float4 c0 = *reinterpret_cast<const float4*>(cb2 + i2 * NCHAN);
        const float4 c1 = *reinterpret_cast<const float4*>(cb2 + i2 * NCHAN + NCHAN);

        float4 acc;
        acc.x = fmaf(w0a, a0.x, w1a * a1.x);
        acc.y = fmaf(w0a, a0.y, w1a * a1.y);
        acc.z = fmaf(w0a, a0.z, w1a * a1.z);
        acc.w = fmaf(w0a, a0.w, w1a * a1.w);
        acc.x = fmaf(w0b, b0.x, fmaf(w1b, b1.x, acc.x));
        acc.y = fmaf(w0b, b0.y, fmaf(w1b, b1.y, acc.y));
        acc.z = fmaf(w0b, b0.z, fmaf(w1b, b1.z, acc.z));
        acc.w = fmaf(w0b, b0.w, fmaf(w1b, b1.w, acc.w));
        acc.x = fmaf(w0c, c0.x, fmaf(w1c, c1.x, acc.x));
        acc.y = fmaf(w0c, c0.y, fmaf(w1c, c1.y, acc.y));
        acc.z = fmaf(w0c, c0.z, fmaf(w1c, c1.z, acc.z));
        acc.w = fmaf(w0c, c0.w, fmaf(w1c, c1.w, acc.w));

        // wave stores 1 KB contiguous
        *reinterpret_cast<float4*>(og + (size_t)lp * NCHAN) = acc;
    }
}

extern "C" void kernel_launch(void* const* d_in, const int* in_sizes, int n_in,
                              void* d_out, int out_size, void* d_ws, size_t ws_size,
                              hipStream_t stream) {
    const float* coords     = (const float*)d_in[0];
    const int*   idx        = (const int*)d_in[1];
    const float* shape_code = (const float*)d_in[2];
    float*       out        = (float*)d_out;
    float*       code_t     = (float*)d_ws;   // 768 KB scratch

    transpose_kernel<<<CODE_T_ELEMS / 256, 256, 0, stream>>>(shape_code, code_t);

    dim3 grid(NB * BLOCKS_PER_BATCH);   // 2048 blocks
    dim3 block(NTHREADS);               // 256 threads
    posenc_kernel<<<grid, block, 0, stream>>>(coords, idx, code_t, out);
}

// Round 7
// 175.238 us; speedup vs baseline: 1.0923x; 1.0923x over previous
//
#include <hip/hip_runtime.h>

// OptPosEncBatch: per-point multi-feature 1D-linear codebook interpolation.
// coords [B=8, P=65536, F=3] f32, idx [B] i32, shape_code [C=64, S*F*CN=3072] f32
// out [B, P, C=64] f32.
//
// R6 counters (L2-direct): 81us, BW 21%, VALUBusy 15%, VGPR 32 -> stall-bound;
// 10 VMEM/wave-iter all through TA/L1, serial chain, multi-batch L1 thrash.
// R7 hybrid: gathers from LDS (lgkm queue ONLY ds_reads -> counted waits work),
// coords from global with explicit next-iter register prefetch (vmcnt queue),
// padded LDS rows (272B) to de-align the 4 groups' bank-quad starts.

#define CODE_NUM 64
#define NFEAT 3
#define NCHAN 64
#define NB 8
#define NP 65536
#define SLICE (CODE_NUM * NFEAT)      // 192 rows in the per-batch slice
#define ROW_STRIDE 3072               // SHAPE_NUM * NFEAT * CODE_NUM
#define ROWF 68                       // padded floats per LDS row (272 B)
#define NTHREADS 512
#define BLOCKS_PER_BATCH 64
#define PTS_PER_BLOCK (NP / BLOCKS_PER_BATCH)   // 1024
#define PTS_PER_ITER (NTHREADS / 16)            // 32
#define NIT (PTS_PER_BLOCK / PTS_PER_ITER)      // 32

__global__ __launch_bounds__(NTHREADS, 6)   // 6 waves/EU -> VGPR<=85, 3 blocks/CU max
void posenc_kernel(const float* __restrict__ coords,
                   const int* __restrict__ idx,
                   const float* __restrict__ shape_code,
                   float* __restrict__ out) {
    __shared__ float code_lds[SLICE * ROWF];   // 52224 B

    const int bx    = blockIdx.x;
    const int b     = bx >> 6;                  // batch
    const int chunk = (bx & (BLOCKS_PER_BATCH - 1)) * PTS_PER_BLOCK;
    const int tid   = threadIdx.x;
    const size_t bp0 = (size_t)b * NP;

    // --- stage shape_code[c][base .. base+191] -> code_lds[j][c] (padded rows) ---
    const int base = idx[b] * SLICE;
    {
        const int c      = tid & 63;
        const int jchunk = tid >> 6;            // 0..7
        const float* src = shape_code + (size_t)c * ROW_STRIDE + base;
        #pragma unroll
        for (int jv = jchunk; jv < SLICE / 4; jv += NTHREADS / 64) {
            const float4 v = *reinterpret_cast<const float4*>(src + jv * 4);
            code_lds[(jv * 4 + 0) * ROWF + c] = v.x;
            code_lds[(jv * 4 + 1) * ROWF + c] = v.y;
            code_lds[(jv * 4 + 2) * ROWF + c] = v.z;
            code_lds[(jv * 4 + 3) * ROWF + c] = v.w;
        }
    }
    __syncthreads();

    const int gl   = tid & 15;                  // channel group: channels gl*4..gl*4+3
    const int pofs = tid >> 4;                  // 0..31
    const float* cp = coords + (bp0 + chunk) * NFEAT;
    float*       og = out + (bp0 + chunk) * NCHAN + gl * 4;

    // loop-invariant per-feature LDS bases at this lane's channels
    const int inv0 = 0 * CODE_NUM * ROWF + gl * 4;
    const int inv1 = 1 * CODE_NUM * ROWF + gl * 4;
    const int inv2 = 2 * CODE_NUM * ROWF + gl * 4;

    // prefetch coords for it=0 (vmcnt queue; broadcast across each 16-lane group)
    float x0 = cp[pofs * 3 + 0];
    float x1 = cp[pofs * 3 + 1];
    float x2 = cp[pofs * 3 + 2];

    #pragma unroll 1
    for (int it = 0; it < NIT; ++it) {
        const int lp = it * PTS_PER_ITER + pofs;

        // index math from current coords (already in registers)
        const float g0 = fmaf(x0, 31.5f, 31.5f);
        const float g1 = fmaf(x1, 31.5f, 31.5f);
        const float g2 = fmaf(x2, 31.5f, 31.5f);
        int i0 = (int)floorf(g0); i0 = max(0, min(i0, CODE_NUM - 2));
        int i1 = (int)floorf(g1); i1 = max(0, min(i1, CODE_NUM - 2));
        int i2 = (int)floorf(g2); i2 = max(0, min(i2, CODE_NUM - 2));
        const float w1a = g0 - (float)i0, w0a = 1.0f - w1a;
        const float w1b = g1 - (float)i1, w0b = 1.0f - w1b;
        const float w1c = g2 - (float)i2, w0c = 1.0f - w1c;

        // prefetch next iteration's coords early (independent vmcnt loads,
        // latency hidden under this iteration's gathers+FMAs)
        const int np_ = min(lp + PTS_PER_ITER, PTS_PER_BLOCK - 1);
        x0 = cp[np_ * 3 + 0];
        x1 = cp[np_ * 3 + 1];
        x2 = cp[np_ * 3 + 2];

        // six ds_read_b128 gathers; lgkm queue holds ONLY these -> counted waits
        const float* r0 = &code_lds[inv0 + i0 * ROWF];
        const float* r1 = &code_lds[inv1 + i1 * ROWF];
        const float* r2 = &code_lds[inv2 + i2 * ROWF];
        const float4 a0 = *reinterpret_cast<const float4*>(r0);
        const float4 a1 = *reinterpret_cast<const float4*>(r0 + ROWF);
        const float4 b0 = *reinterpret_cast<const float4*>(r1);
        const float4 b1 = *reinterpret_cast<const float4*>(r1 + ROWF);
        const float4 c0 = *reinterpret_cast<const float4*>(r2);
        const float4 c1 = *reinterpret_cast<const float4*>(r2 + ROWF);

        float4 acc;
        acc.x = fmaf(w0a, a0.x, w1a * a1.x);
        acc.y = fmaf(w0a, a0.y, w1a * a1.y);
        acc.z = fmaf(w0a, a0.z, w1a * a1.z);
        acc.w = fmaf(w0a, a0.w, w1a * a1.w);
        acc.x = fmaf(w0b, b0.x, fmaf(w1b, b1.x, acc.x));
        acc.y = fmaf(w0b, b0.y, fmaf(w1b, b1.y, acc.y));
        acc.z = fmaf(w0b, b0.z, fmaf(w1b, b1.z, acc.z));
        acc.w = fmaf(w0b, b0.w, fmaf(w1b, b1.w, acc.w));
        acc.x = fmaf(w0c, c0.x, fmaf(w1c, c1.x, acc.x));
        acc.y = fmaf(w0c, c0.y, fmaf(w1c, c1.y, acc.y));
        acc.z = fmaf(w0c, c0.z, fmaf(w1c, c1.z, acc.z));
        acc.w = fmaf(w0c, c0.w, fmaf(w1c, c1.w, acc.w));

        // wave stores 1 KB contiguous (fire-and-forget, vmcnt queue)
        *reinterpret_cast<float4*>(og + (size_t)lp * NCHAN) = acc;
    }
}

extern "C" void kernel_launch(void* const* d_in, const int* in_sizes, int n_in,
                              void* d_out, int out_size, void* d_ws, size_t ws_size,
                              hipStream_t stream) {
    const float* coords     = (const float*)d_in[0];
    const int*   idx        = (const int*)d_in[1];
    const float* shape_code = (const float*)d_in[2];
    float*       out        = (float*)d_out;

    dim3 grid(NB * BLOCKS_PER_BATCH);   // 512 blocks
    dim3 block(NTHREADS);               // 512 threads
    posenc_kernel<<<grid, block, 0, stream>>>(coords, idx, shape_code, out);
}

// Round 11
// 151.174 us; speedup vs baseline: 1.2662x; 1.1592x over previous
//
#include <hip/hip_runtime.h>

// OptPosEncBatch: per-point multi-feature 1D-linear codebook interpolation.
// coords [B=8, P=65536, F=3] f32, idx [B] i32, shape_code [C=64, S*F*CN=3072] f32
// out [B, P, C=64] f32.
//
// R7 post-mortem: queue split (coords->vmcnt, gathers->lgkm) alone didn't help
// because gathers were issued AND consumed in the same iteration -- 120cy DS
// latency exposed per iter. R8 = R4's issue-ahead pipeline x R7's global
// coords: lgkm queue holds ONLY gathers, so issuing frag(it+1) before
// consuming frag(it) lets the compiler emit counted lgkmcnt(6) waits.
// Even/odd frag register sets (no runtime indexing), coords 2-3 iters ahead.

#define CODE_NUM 64
#define NFEAT 3
#define NCHAN 64
#define NB 8
#define NP 65536
#define SLICE (CODE_NUM * NFEAT)      // 192 rows in the per-batch slice
#define ROW_STRIDE 3072               // SHAPE_NUM * NFEAT * CODE_NUM
#define NTHREADS 512
#define BLOCKS_PER_BATCH 64
#define PTS_PER_BLOCK (NP / BLOCKS_PER_BATCH)   // 1024
#define PTS_PER_ITER (NTHREADS / 16)            // 32
#define NIT (PTS_PER_BLOCK / PTS_PER_ITER)      // 32

__global__ __launch_bounds__(NTHREADS, 4)   // 128-VGPR cap, 16 waves/CU (2 blocks)
void posenc_kernel(const float* __restrict__ coords,
                   const int* __restrict__ idx,
                   const float* __restrict__ shape_code,
                   float* __restrict__ out) {
    __shared__ float code_lds[SLICE * NCHAN];   // [row][chan] unpadded, 48 KB
                                                // (256B-row b128 reads: uniform
                                                // bank coverage, pad useless;
                                                // measured conflicts = 0)

    const int bx    = blockIdx.x;
    const int b     = bx >> 6;
    const int chunk = (bx & (BLOCKS_PER_BATCH - 1)) * PTS_PER_BLOCK;
    const int tid   = threadIdx.x;
    const size_t bp0 = (size_t)b * NP;

    // --- stage shape_code[c][base .. base+191] -> code_lds[j][c] ---
    const int base = idx[b] * SLICE;
    {
        const int c      = tid & 63;
        const int jchunk = tid >> 6;
        const float* src = shape_code + (size_t)c * ROW_STRIDE + base;
        #pragma unroll
        for (int jv = jchunk; jv < SLICE / 4; jv += NTHREADS / 64) {
            const float4 v = *reinterpret_cast<const float4*>(src + jv * 4);
            code_lds[(jv * 4 + 0) * NCHAN + c] = v.x;
            code_lds[(jv * 4 + 1) * NCHAN + c] = v.y;
            code_lds[(jv * 4 + 2) * NCHAN + c] = v.z;
            code_lds[(jv * 4 + 3) * NCHAN + c] = v.w;
        }
    }
    __syncthreads();

    const int gl   = tid & 15;
    const int pofs = tid >> 4;                  // 0..31
    const float* cp = coords + (bp0 + chunk) * NFEAT;
    float*       og = out + (bp0 + chunk) * NCHAN + gl * 4;

    const int inv0 = 0 * CODE_NUM * NCHAN + gl * 4;
    const int inv1 = 1 * CODE_NUM * NCHAN + gl * 4;
    const int inv2 = 2 * CODE_NUM * NCHAN + gl * 4;

// load coords for iteration IT into three named regs (vmcnt queue)
#define LOADC(IT, X0, X1, X2)                                                  \
    {                                                                          \
        const int _lp = (IT) * PTS_PER_ITER + pofs;                            \
        X0 = cp[_lp * 3 + 0];                                                  \
        X1 = cp[_lp * 3 + 1];                                                  \
        X2 = cp[_lp * 3 + 2];                                                  \
    }

// index math + issue 6 ds_read_b128 into the named frag (lgkm queue)
#define ISSUE(X0, X1, X2, F0, F1, F2, F3, F4, F5, W0, W1, W2)                  \
    {                                                                          \
        const float g0 = fmaf(X0, 31.5f, 31.5f);                               \
        const float g1 = fmaf(X1, 31.5f, 31.5f);                               \
        const float g2 = fmaf(X2, 31.5f, 31.5f);                               \
        int i0 = (int)floorf(g0); i0 = max(0, min(i0, CODE_NUM - 2));          \
        int i1 = (int)floorf(g1); i1 = max(0, min(i1, CODE_NUM - 2));          \
        int i2 = (int)floorf(g2); i2 = max(0, min(i2, CODE_NUM - 2));          \
        W0 = g0 - (float)i0;                                                   \
        W1 = g1 - (float)i1;                                                   \
        W2 = g2 - (float)i2;                                                   \
        const float* r0 = &code_lds[inv0 + i0 * NCHAN];                        \
        const float* r1 = &code_lds[inv1 + i1 * NCHAN];                        \
        const float* r2 = &code_lds[inv2 + i2 * NCHAN];                        \
        F0 = *reinterpret_cast<const float4*>(r0);                             \
        F1 = *reinterpret_cast<const float4*>(r0 + NCHAN);                     \
        F2 = *reinterpret_cast<const float4*>(r1);                             \
        F3 = *reinterpret_cast<const float4*>(r1 + NCHAN);                     \
        F4 = *reinterpret_cast<const float4*>(r2);                             \
        F5 = *reinterpret_cast<const float4*>(r2 + NCHAN);                     \
    }

// weighted reduce + 1KB coalesced store
#define CONSUME(IT, F0, F1, F2, F3, F4, F5, W0, W1, W2)                        \
    {                                                                          \
        const float u0 = 1.0f - W0, u1 = 1.0f - W1, u2 = 1.0f - W2;            \
        float4 acc;                                                            \
        acc.x = fmaf(u0, F0.x, W0 * F1.x);                                     \
        acc.y = fmaf(u0, F0.y, W0 * F1.y);                                     \
        acc.z = fmaf(u0, F0.z, W0 * F1.z);                                     \
        acc.w = fmaf(u0, F0.w, W0 * F1.w);                                     \
        acc.x = fmaf(u1, F2.x, fmaf(W1, F3.x, acc.x));                         \
        acc.y = fmaf(u1, F2.y, fmaf(W1, F3.y, acc.y));                         \
        acc.z = fmaf(u1, F2.z, fmaf(W1, F3.z, acc.z));                         \
        acc.w = fmaf(u1, F2.w, fmaf(W1, F3.w, acc.w));                         \
        acc.x = fmaf(u2, F4.x, fmaf(W2, F5.x, acc.x));                         \
        acc.y = fmaf(u2, F4.y, fmaf(W2, F5.y, acc.y));                         \
        acc.z = fmaf(u2, F4.z, fmaf(W2, F5.z, acc.z));                         \
        acc.w = fmaf(u2, F4.w, fmaf(W2, F5.w, acc.w));                         \
        *reinterpret_cast<float4*>(og + (size_t)((IT) * PTS_PER_ITER + pofs) * NCHAN) = acc; \
    }

    float4 A0, A1, A2, A3, A4, A5, B0, B1, B2, B3, B4, B5;
    float  wa0, wa1, wa2, wb0, wb1, wb2;
    float  cA0, cA1, cA2, cB0, cB1, cB2;

    // prologue: coords(0), coords(1); issue frag(0)
    LOADC(0, cA0, cA1, cA2);
    LOADC(1, cB0, cB1, cB2);
    ISSUE(cA0, cA1, cA2, A0, A1, A2, A3, A4, A5, wa0, wa1, wa2);

    // steady state per pair (it, it+1), it = 0,2,...,NIT-4:
    //   coords(it+2) -> cA; issue frag(it+1) from cB; consume frag(it);
    //   coords(it+3) -> cB; issue frag(it+2) from cA; consume frag(it+1).
    #pragma unroll 1
    for (int it = 0; it <= NIT - 4; it += 2) {
        LOADC(it + 2, cA0, cA1, cA2);
        ISSUE(cB0, cB1, cB2, B0, B1, B2, B3, B4, B5, wb0, wb1, wb2);
        CONSUME(it, A0, A1, A2, A3, A4, A5, wa0, wa1, wa2);
        LOADC(it + 3, cB0, cB1, cB2);
        ISSUE(cA0, cA1, cA2, A0, A1, A2, A3, A4, A5, wa0, wa1, wa2);
        CONSUME(it + 1, B0, B1, B2, B3, B4, B5, wb0, wb1, wb2);
    }

    // epilogue: FA holds frag(NIT-2), cB holds coords(NIT-1)
    ISSUE(cB0, cB1, cB2, B0, B1, B2, B3, B4, B5, wb0, wb1, wb2);
    CONSUME(NIT - 2, A0, A1, A2, A3, A4, A5, wa0, wa1, wa2);
    CONSUME(NIT - 1, B0, B1, B2, B3, B4, B5, wb0, wb1, wb2);

#undef LOADC
#undef ISSUE
#undef CONSUME
}

extern "C" void kernel_launch(void* const* d_in, const int* in_sizes, int n_in,
                              void* d_out, int out_size, void* d_ws, size_t ws_size,
                              hipStream_t stream) {
    const float* coords     = (const float*)d_in[0];
    const int*   idx        = (const int*)d_in[1];
    const float* shape_code = (const float*)d_in[2];
    float*       out        = (float*)d_out;

    dim3 grid(NB * BLOCKS_PER_BATCH);   // 512 blocks
    dim3 block(NTHREADS);               // 512 threads
    posenc_kernel<<<grid, block, 0, stream>>>(coords, idx, shape_code, out);
}